// Round 10
// baseline (200.065 us; speedup 1.0000x reference)
//
#include <hip/hip_runtime.h>
#include <math.h>

// Problem constants
constexpr int B = 8;
constexpr int D = 256;     // model dim
constexpr int C = 1024;    // expanded channels
constexpr int H = 32, W = 32;
constexpr int P = H * W;            // 1024 spatial positions
constexpr int M = B * P;            // 8192 rows
constexpr float EPS = 1e-5f;

typedef unsigned short u16;
typedef unsigned int u32;
typedef __attribute__((ext_vector_type(8))) short short8;
typedef __attribute__((ext_vector_type(4))) float floatx4;

// ---------------- workspace layout (in floats) ----------------
constexpr size_t WS_CHSUM1 = 0;                  // 1024
constexpr size_t WS_CHSQ1  = 1024;               // 1024
constexpr size_t WS_GAPSUM = 2048;               // 8192
constexpr size_t WS_CHSUM3 = 10240;              // 256
constexpr size_t WS_CHSQ3  = 10496;              // 256
constexpr size_t WS_CHSUM2 = 10752;              // 1024
constexpr size_t WS_CHSQ2  = 11776;              // 1024
constexpr size_t WS_BSUM2  = 12800;              // 8192
constexpr size_t WS_UMAX2  = 20992;              // 8192 (u32 keys)
constexpr size_t WS_UMAXN2 = 29184;              // 8192 (u32 keys of -min)
constexpr size_t WS_ACC_COUNT = 37376;
constexpr size_t WS_SCALE1 = 37376;              // 1024
constexpr size_t WS_SHIFT1 = 38400;              // 1024
constexpr size_t WS_KW     = 39424;              // 256 (72 used)
constexpr size_t WS_SCALE2 = 39680;              // 1024
constexpr size_t WS_SHIFT2 = 40704;              // 1024
constexpr size_t WS_SATT   = 41728;              // 8192
constexpr size_t WS_AVGO   = 49920;              // 8192
constexpr size_t WS_MAXO   = 58112;              // 8192
constexpr size_t WS_SP     = 66304;              // (unused, kept for layout stability)
constexpr size_t WS_PRE    = 74496;              // 2097152
constexpr size_t WS_T1B    = 2171648;            // bf16 t1
constexpr size_t WS_T2B    = 6365952;            // bf16 t2
constexpr size_t WS_XB     = 10560256;           // bf16 x
constexpr size_t WS_W1B    = 11608832;
constexpr size_t WS_PWB    = 11739904;           // (unused, kept for layout stability)
constexpr size_t WS_PWBF   = 11870976;           // folded per-batch weights, 8x256x1024 bf16
constexpr size_t WS_BIAS2  = 12919552;           // 2048 floats (8x256), pb NOT included

__device__ __forceinline__ float gelu_exact(float v) {
    return 0.5f * v * (1.0f + erff(v * 0.70710678118654752440f));
}

__device__ __forceinline__ u16 f2bf(float f) {
    u32 u = __float_as_uint(f);
    u += 0x7fff + ((u >> 16) & 1);   // round-to-nearest-even
    return (u16)(u >> 16);
}

__device__ __forceinline__ float bf2f(u16 v) {
    return __uint_as_float(((u32)v) << 16);
}

// order-preserving float->u32 key
__device__ __forceinline__ u32 fkey(float f) {
    u32 u = __float_as_uint(f);
    return (u & 0x80000000u) ? ~u : (u | 0x80000000u);
}
__device__ __forceinline__ float fkeyinv(u32 k) {
    return __uint_as_float((k & 0x80000000u) ? (k ^ 0x80000000u) : ~k);
}

#define GLOAD(SRC, DST) __builtin_amdgcn_global_load_lds( \
    (const __attribute__((address_space(1))) void*)(SRC), \
    (__attribute__((address_space(3))) void*)(DST), 16, 0, 0)

// ---------------- K0: zero accumulators + cast fp32 -> bf16 for x, w1 ----------------
__global__ __launch_bounds__(256) void cvt_all_kernel(const float* __restrict__ x,
                                                      const float* __restrict__ w1,
                                                      u16* __restrict__ xb,
                                                      u16* __restrict__ w1b,
                                                      float* __restrict__ acc_zero) {
    const int i = blockIdx.x * 256 + threadIdx.x;     // grid covers 589824
    if (i < (int)WS_ACC_COUNT) acc_zero[i] = 0.f;     // 0x0 == fkey floor for max-keys too
    const float* src;
    u16* dst;
    int off;
    if (i < 524288) { src = x;  dst = xb;  off = i; }
    else            { src = w1; dst = w1b; off = i - 524288; }
    const float4 v = *(const float4*)(src + (size_t)off * 4);
    uint2 o;
    o.x = ((u32)f2bf(v.x)) | ((u32)f2bf(v.y) << 16);
    o.y = ((u32)f2bf(v.z)) | ((u32)f2bf(v.w) << 16);
    *(uint2*)(dst + (size_t)off * 4) = o;
}

// ---------------- MFMA bf16 GEMM — 3-buffer 2-deep pipeline + intra-block K-split -------
// WSPLIT=1 (gemm1): 256 threads, 4 waves, one pipeline over all NCH chunks.
// WSPLIT=2 (gemm2): 512 threads, 8 waves in 2 groups; group g pipelines K-range
//   [g*KD/2, (g+1)*KD/2) in its OWN 3-buffer LDS region; group 1 dumps acc via LDS,
//   group 0 adds.
// Per chunk: stage(c+2) -> vmcnt(6) -> barrier -> setprio(1) MFMA setprio(0) ->
// lgkmcnt(0) -> barrier.  T5 setprio: the counted-vmcnt pipeline gives waves distinct
// roles (stage-issuing vs MFMA-entering) -> scheduler can favor the MFMA wave (m218b).
// EPI 0: t = gelu(acc+bias); bf16 out; col stats + gsum.  Shared B, shared bias.
// EPI 1: t = sp*(acc+bias) + bias_post; fp32 out; col stats. PER-BATCH B (folded pwb).
//        sp (7x7 spatial conv + sigmoid) computed in-kernel from avg_o/max_o.
template<int KD, int EPI, int NS, int MB, int NB, int WSPLIT>
__global__ __launch_bounds__(256 * WSPLIT) void mfma_gemm_kernel(
    const u16* __restrict__ A,
    const u16* __restrict__ Bw,
    const float* __restrict__ bias,
    const float* __restrict__ bias_post,
    const float* __restrict__ avg_o,
    const float* __restrict__ max_o,
    const float* __restrict__ swp,
    const float* __restrict__ sbp,
    void* __restrict__ outv,
    float* __restrict__ csum,
    float* __restrict__ csq,
    float* __restrict__ gsum)
{
    constexpr int NT = 256 * WSPLIT;
    constexpr int MI = MB / 32;
    constexpr int NJ = NB / 32;
    constexpr int ABUF = MB * 32;
    constexpr int BBUF = NB * 32;
    constexpr int BUFSZ = ABUF + BBUF;
    constexpr int GA = MB / 64;
    constexpr int GB = NB / 64;
    constexpr int LD = GA + GB;
    static_assert(LD == 3, "vmcnt literals assume 3 loads per chunk");
    constexpr int NCH = KD / 32;
    constexpr int NCHG = NCH / WSPLIT;   // chunks per wave-group
    constexpr int GX = NS / NB;
    constexpr int NWG = (M / MB) * GX;   // %8 == 0 for both instantiations
    constexpr int CPX = NWG / 8;
    extern __shared__ u16 smem[];
    const int t = threadIdx.x;
    const int lane = t & 63;
    const int wv = t >> 6;
    const int grp = (WSPLIT == 2) ? (wv >> 2) : 0;
    const int wg = wv & 3;               // wave index within group
    const int tg = t & 255;              // thread index within group

    // XCD-chunked bijective block swizzle
    const int lin = blockIdx.y * GX + blockIdx.x;
    const int swz = (lin & 7) * CPX + (lin >> 3);
    const int bx = swz % GX;
    const int by = swz / GX;
    const int row0 = by * MB;
    const int col0 = bx * NB;
    const int bb = row0 >> 10;           // batch index (MB divides 1024)

    const int wrow = (wg >> 1) * (MB / 2);
    const int wcol = (wg & 1) * (NB / 2);
    const int lm = lane & 15;
    const int lk8 = (lane >> 4) * 8;
    const int srow = tg >> 2;
    const int scol = (tg & 3) * 8;
    const u16* gA = A + (size_t)(row0 + srow) * KD + scol;
    const u16* gB = Bw + (EPI == 1 ? (size_t)bb * NS * KD : (size_t)0)
                       + (size_t)(col0 + srow) * KD + scol;
    const float* biasp = bias + (EPI == 1 ? bb * NS : 0);

    u16* gsmem = smem + grp * (3 * BUFSZ);
    const int kbase = grp * NCHG;        // first chunk of this group's K-range

    const floatx4 zero = {0.f, 0.f, 0.f, 0.f};
    floatx4 acc[MI][NJ];
#pragma unroll
    for (int i = 0; i < MI; ++i)
#pragma unroll
        for (int j = 0; j < NJ; ++j) acc[i][j] = zero;

    auto stage = [&](u16* buf, int c) {
        const int kk = (kbase + c) * 32;
        u16* As = buf;
        u16* Bs = buf + ABUF;
#pragma unroll
        for (int g = 0; g < GA; ++g)
            GLOAD(gA + (size_t)g * 64 * KD + kk, As + g * 2048 + tg * 8);
#pragma unroll
        for (int g = 0; g < GB; ++g)
            GLOAD(gB + (size_t)g * 64 * KD + kk, Bs + g * 2048 + tg * 8);
    };
    auto compute = [&](const u16* buf) {
        const u16* As = buf;
        const u16* Bs = buf + ABUF;
        short8 af[MI], bf[NJ];
#pragma unroll
        for (int i = 0; i < MI; ++i)
            af[i] = *(const short8*)(As + (wrow + i * 16 + lm) * 32 + lk8);
#pragma unroll
        for (int j = 0; j < NJ; ++j)
            bf[j] = *(const short8*)(Bs + (wcol + j * 16 + lm) * 32 + lk8);
        __builtin_amdgcn_s_setprio(1);
#pragma unroll
        for (int i = 0; i < MI; ++i)
#pragma unroll
            for (int j = 0; j < NJ; ++j)
                acc[i][j] = __builtin_amdgcn_mfma_f32_16x16x32_bf16(af[i], bf[j], acc[i][j], 0, 0, 0);
        __builtin_amdgcn_s_setprio(0);
    };

    stage(gsmem, 0);
    if (NCHG > 1) stage(gsmem + BUFSZ, 1);

    // EPI1 prologue: compute sp for this block's 128 rows (4 h-rows of batch bb).
    // LDS ext region above all staging buffers: pa[320], pm[320], sw[98], sp@768[128].
    float* ext = (float*)(smem + (size_t)WSPLIT * 3 * BUFSZ);
    if constexpr (EPI == 1) {
        const int p0 = (by & 7) * MB;        // first pixel of tile (MB==128)
        const int h0 = p0 >> 5;              // first h row
        const int bbase = bb * P;
        for (int e = t; e < 640; e += NT) {
            const bool isM = e >= 320;
            const int idx = isM ? e - 320 : e;
            const int r = idx >> 5, w = idx & 31;
            const int hh = h0 - 3 + r;
            float v = 0.f;
            if (hh >= 0 && hh < H) v = (isM ? max_o : avg_o)[bbase + hh * W + w];
            ext[e] = v;
        }
        if (t < 98) ext[640 + t] = swp[t];
        __syncthreads();
        if (t < 128) {
            const int hl = t >> 5, w = t & 31;
            float a = sbp[0];
#pragma unroll
            for (int i = 0; i < 7; ++i) {
                const int r = hl + i;        // pa row (h0+hl+i-3), zero-padded out of range
#pragma unroll
                for (int j = 0; j < 7; ++j) {
                    const int ww = w + j - 3;
                    if (ww < 0 || ww >= W) continue;
                    a = fmaf(ext[640 + i * 7 + j], ext[r * 32 + ww], a);
                    a = fmaf(ext[640 + 49 + i * 7 + j], ext[320 + r * 32 + ww], a);
                }
            }
            ext[768 + t] = 1.0f / (1.0f + expf(-a));
        }
    }

    int cur = 0;
    for (int c = 0; c < NCHG; ++c) {
        if (c + 2 < NCHG) {
            const int nb3 = (cur + 2 >= 3) ? cur - 1 : cur + 2;
            stage(gsmem + nb3 * BUFSZ, c + 2);
            asm volatile("s_waitcnt vmcnt(6)" ::: "memory");
        } else if (c + 1 < NCHG) {
            asm volatile("s_waitcnt vmcnt(3)" ::: "memory");
        } else {
            asm volatile("s_waitcnt vmcnt(0)" ::: "memory");
        }
        __builtin_amdgcn_s_barrier();
        compute(gsmem + cur * BUFSZ);
        asm volatile("s_waitcnt lgkmcnt(0)" ::: "memory");
        __builtin_amdgcn_s_barrier();
        cur = (cur + 1 >= 3) ? 0 : cur + 1;
    }

    // K-split reduction: group 1 dumps acc via LDS (its own staging region), group 0 adds.
    if constexpr (WSPLIT == 2) {
        float* red = (float*)(smem + 3 * BUFSZ);   // 32KB fits in group1's 36864B region
        if (grp == 1) {
#pragma unroll
            for (int i = 0; i < MI; ++i)
#pragma unroll
                for (int r = 0; r < 4; ++r) {
                    const int lrow = wrow + i * 16 + (lane >> 4) * 4 + r;
#pragma unroll
                    for (int j = 0; j < NJ; ++j)
                        red[lrow * NB + wcol + j * 16 + lm] = acc[i][j][r];
                }
        }
        __syncthreads();
        if (grp == 0) {
#pragma unroll
            for (int i = 0; i < MI; ++i)
#pragma unroll
                for (int r = 0; r < 4; ++r) {
                    const int lrow = wrow + i * 16 + (lane >> 4) * 4 + r;
#pragma unroll
                    for (int j = 0; j < NJ; ++j)
                        acc[i][j][r] += red[lrow * NB + wcol + j * 16 + lm];
                }
        }
        __syncthreads();
    }

    float colsum[NJ], colsq[NJ];
#pragma unroll
    for (int j = 0; j < NJ; ++j) { colsum[j] = 0.f; colsq[j] = 0.f; }

    if (EPI == 0) {
        u16* Cs = smem;
#pragma unroll
        for (int i = 0; i < MI; ++i) {
#pragma unroll
            for (int r = 0; r < 4; ++r) {
                const int lrow = wrow + i * 16 + (lane >> 4) * 4 + r;
#pragma unroll
                for (int j = 0; j < NJ; ++j) {
                    const int lcol = wcol + j * 16 + lm;
                    const float tv = gelu_exact(acc[i][j][r] + biasp[col0 + lcol]);
                    Cs[lrow * NB + lcol] = f2bf(tv);
                    colsum[j] += tv;
                    colsq[j] = fmaf(tv, tv, colsq[j]);
                }
            }
        }
        __syncthreads();
        constexpr int TPR = NB / 8;
        constexpr int RPP = NT / TPR;
        u16* outp = (u16*)outv;
#pragma unroll
        for (int pp = 0; pp < MB / RPP; ++pp) {
            const int r = pp * RPP + t / TPR;
            const int cc = (t % TPR) * 8;
            *(uint4*)(outp + (size_t)(row0 + r) * NS + col0 + cc) =
                *(const uint4*)(Cs + r * NB + cc);
        }
    } else {
        float* Cs = (float*)smem;            // 32KB at base; ext and red are above it
        if (grp == 0) {
#pragma unroll
            for (int i = 0; i < MI; ++i) {
#pragma unroll
                for (int r = 0; r < 4; ++r) {
                    const int lrow = wrow + i * 16 + (lane >> 4) * 4 + r;
                    const float rs = ext[768 + lrow];
#pragma unroll
                    for (int j = 0; j < NJ; ++j) {
                        const int lcol = wcol + j * 16 + lm;
                        const float tv = rs * (acc[i][j][r] + biasp[col0 + lcol])
                                       + bias_post[col0 + lcol];
                        Cs[lrow * NB + lcol] = tv;
                        colsum[j] += tv;
                        colsq[j] = fmaf(tv, tv, colsq[j]);
                    }
                }
            }
        }
        __syncthreads();
        constexpr int TPR = NB / 4;
        constexpr int RPP = NT / TPR;
        float* outp = (float*)outv;
#pragma unroll
        for (int pp = 0; pp < MB / RPP; ++pp) {
            const int r = pp * RPP + t / TPR;
            const int cc = (t % TPR) * 4;
            *(float4*)(outp + (size_t)(row0 + r) * NS + col0 + cc) =
                *(const float4*)(Cs + r * NB + cc);
        }
    }

#pragma unroll
    for (int j = 0; j < NJ; ++j) {
        float s = colsum[j];
        float q = colsq[j];
        s += __shfl_xor(s, 16); s += __shfl_xor(s, 32);
        q += __shfl_xor(q, 16); q += __shfl_xor(q, 32);
        if (grp == 0 && lane < 16) {
            const int c = col0 + wcol + j * 16 + lm;
            atomicAdd(&csum[c], s);
            atomicAdd(&csq[c], q);
            if (EPI == 0) atomicAdd(&gsum[bb * NS + c], s);
        }
    }
}

// ---------------- K4: dynamic kernel MLP + fused BN1 stats ----------------
__global__ __launch_bounds__(1024) void dynmlp_kernel(const float* __restrict__ chsum1,
                                                      const float* __restrict__ chsq1,
                                                      const float* __restrict__ gapsum,
                                                      const float* __restrict__ g1,
                                                      const float* __restrict__ be1,
                                                      const float* __restrict__ aw1,
                                                      const float* __restrict__ ab1,
                                                      const float* __restrict__ aw2,
                                                      const float* __restrict__ ab2,
                                                      float* __restrict__ scale1,
                                                      float* __restrict__ shift1,
                                                      float* __restrict__ kw) {
    const int b = blockIdx.x;
    const int t = threadIdx.x;
    const int wave = t >> 6, lane = t & 63;
    __shared__ float g[1024];
    __shared__ float h1[128];
    __shared__ float logits[12];
    {
        const float m = chsum1[t] * (1.0f / (float)M);
        const float var = chsq1[t] * (1.0f / (float)M) - m * m;
        const float rstd = rsqrtf(var + EPS);
        const float sc = rstd * g1[t];
        const float sh = be1[t] - m * sc;
        if (b == 0) { scale1[t] = sc; shift1[t] = sh; }
        g[t] = gapsum[b * C + t] * (1.0f / (float)P) * sc + sh;
    }
    __syncthreads();
#pragma unroll
    for (int k = 0; k < 8; ++k) {
        const int u = wave * 8 + k;
        const float4* wr = (const float4*)(aw1 + (size_t)u * C);
        float s = 0.f;
#pragma unroll
        for (int ch = 0; ch < 4; ++ch) {
            const float4 wv = wr[lane + 64 * ch];
            const float4 sv = *(const float4*)(g + 4 * lane + 256 * ch);
            s += wv.x * sv.x + wv.y * sv.y + wv.z * sv.z + wv.w * sv.w;
        }
#pragma unroll
        for (int off = 1; off < 64; off <<= 1) s += __shfl_xor(s, off);
        if (lane == 0) h1[u] = fmaxf(s + ab1[u], 0.f);
    }
    __syncthreads();
    if (wave < 9) {
        float s = aw2[wave * 128 + lane] * h1[lane]
                + aw2[wave * 128 + 64 + lane] * h1[64 + lane];
#pragma unroll
        for (int off = 1; off < 64; off <<= 1) s += __shfl_xor(s, off);
        if (lane == 0) logits[wave] = s + ab2[wave];
    }
    __syncthreads();
    if (t == 0) {
        float mx = logits[0];
        for (int i = 1; i < 9; ++i) mx = fmaxf(mx, logits[i]);
        float e[9], den = 0.f;
        for (int i = 0; i < 9; ++i) { e[i] = expf(logits[i] - mx); den += e[i]; }
        const float inv = 1.0f / den;
        for (int i = 0; i < 9; ++i) kw[b * 9 + i] = e[i] * inv;
    }
}

// ---------------- K5: dyn depthwise conv — sliding-window regs, h-band XCD swizzle ------
__global__ __launch_bounds__(256) void dwconv_kernel(const u16* __restrict__ t1b,
                                                     const float* __restrict__ scale1,
                                                     const float* __restrict__ shift1,
                                                     const float* __restrict__ kw,
                                                     u16* __restrict__ t2b,
                                                     float* __restrict__ chsum2,
                                                     float* __restrict__ chsq2,
                                                     float* __restrict__ bsum2,
                                                     u32* __restrict__ umax2,
                                                     u32* __restrict__ umaxn2) {
    __shared__ u16 rows[3 * 32 * 256];   // 48 KB: [r][w][ch]
    const int lin = blockIdx.y * 4 + blockIdx.x;     // nwg = 1024
    const int xcd = lin & 7;
    const int i7 = lin >> 3;             // 0..127
    const int b = i7 >> 4;
    const int r4 = i7 & 15;
    const int h = xcd * 4 + (r4 >> 2);
    const int cq = r4 & 3;
    const int t = threadIdx.x;

    const u16* gbase = t1b + (size_t)b * P * C + cq * 256;
#pragma unroll
    for (int i = 0; i < 12; ++i) {
        const int lin2 = i * 256 + t;
        const int chunk = lin2 >> 5;
        const int r = chunk >> 5;
        const int w = chunk & 31;
        const int off8 = (lin2 & 31) * 8;
        const int hr = h + r - 1;
        uint4 v = {0u, 0u, 0u, 0u};
        if (hr >= 0 && hr < H)
            v = *(const uint4*)(gbase + (size_t)(hr * W + w) * C + off8);
        *(uint4*)(&rows[chunk * 256 + off8]) = v;
    }
    __syncthreads();

    const int c = t;
    const int gc = cq * 256 + c;
    float kk[9];
#pragma unroll
    for (int i = 0; i < 9; ++i) kk[i] = kw[b * 9 + i];
    const float sc = scale1[gc];
    const float sh = shift1[gc];
    float scm[3], shm[3];
    scm[0] = (h > 0)     ? sc : 0.f;  shm[0] = (h > 0)     ? sh : 0.f;
    scm[1] = sc;                      shm[1] = sh;
    scm[2] = (h < H - 1) ? sc : 0.f;  shm[2] = (h < H - 1) ? sh : 0.f;

    const u16* rp0 = rows + c;
#define DWVAL(ri, w) fmaf(bf2f(rp0[((ri) * 32 + (w)) * 256]), scm[ri], shm[ri])

    float vm0 = 0.f, vm1 = 0.f, vm2 = 0.f;
    float vc0 = DWVAL(0, 0), vc1 = DWVAL(1, 0), vc2 = DWVAL(2, 0);
    float vp0 = DWVAL(0, 1), vp1 = DWVAL(1, 1), vp2 = DWVAL(2, 1);

    float s = 0.f, q = 0.f, mx = -INFINITY, mn = INFINITY;
    u16* orow = t2b + ((size_t)b * P + h * W) * C + gc;
    for (int w = 0; w < W; ++w) {
        float acc;
        acc = kk[0] * vm0;
        acc = fmaf(kk[1], vc0, acc);
        acc = fmaf(kk[2], vp0, acc);
        acc = fmaf(kk[3], vm1, acc);
        acc = fmaf(kk[4], vc1, acc);
        acc = fmaf(kk[5], vp1, acc);
        acc = fmaf(kk[6], vm2, acc);
        acc = fmaf(kk[7], vc2, acc);
        acc = fmaf(kk[8], vp2, acc);
        const float y = gelu_exact(acc);
        orow[(size_t)w * C] = f2bf(y);
        s += y;
        q = fmaf(y, y, q);
        mx = fmaxf(mx, y);
        mn = fminf(mn, y);
        vm0 = vc0; vc0 = vp0;
        vm1 = vc1; vc1 = vp1;
        vm2 = vc2; vc2 = vp2;
        if (w + 2 < W) {
            vp0 = DWVAL(0, w + 2);
            vp1 = DWVAL(1, w + 2);
            vp2 = DWVAL(2, w + 2);
        } else {
            vp0 = 0.f; vp1 = 0.f; vp2 = 0.f;
        }
    }
#undef DWVAL
    atomicAdd(&chsum2[gc], s);
    atomicAdd(&chsq2[gc], q);
    atomicAdd(&bsum2[b * C + gc], s);
    atomicMax(&umax2[b * C + gc], fkey(mx));
    atomicMax(&umaxn2[b * C + gc], fkey(-mn));
}

// ---------------- K8: channel attention + O(1) BN2 finalize (s_att only) ----------------
__global__ __launch_bounds__(1024) void chatt_kernel(const float* __restrict__ chsum2,
                                                     const float* __restrict__ chsq2,
                                                     const float* __restrict__ bsum2,
                                                     const u32* __restrict__ umax2,
                                                     const u32* __restrict__ umaxn2,
                                                     const float* __restrict__ g2,
                                                     const float* __restrict__ be2,
                                                     const float* __restrict__ caw1,
                                                     const float* __restrict__ caw2,
                                                     float* __restrict__ scale2,
                                                     float* __restrict__ shift2,
                                                     float* __restrict__ s_att) {
    const int b = blockIdx.x;
    const int t = threadIdx.x;          // channel
    const int wave = t >> 6, lane = t & 63;
    __shared__ float la[1024], lx[1024], ha[64], hm[64];
    {
        const float m = chsum2[t] * (1.0f / (float)M);
        const float var = chsq2[t] * (1.0f / (float)M) - m * m;
        const float rstd = rsqrtf(var + EPS);
        const float sc = rstd * g2[t];
        const float sh = be2[t] - m * sc;
        if (b == 0) { scale2[t] = sc; shift2[t] = sh; }
        la[t] = bsum2[b * C + t] * (1.0f / (float)P) * sc + sh;
        const float mx = fkeyinv(umax2[b * C + t]);
        const float mn = -fkeyinv(umaxn2[b * C + t]);
        lx[t] = (sc >= 0.f ? mx : mn) * sc + sh;
    }
    __syncthreads();
#pragma unroll
    for (int k = 0; k < 8; ++k) {
        const int u = wave * 8 + k;
        const int row = u & 63;
        const float* src = (u < 64) ? la : lx;
        const float4* wr = (const float4*)(caw1 + (size_t)row * C);
        float s = 0.f;
#pragma unroll
        for (int ch = 0; ch < 4; ++ch) {
            const float4 wv = wr[lane + 64 * ch];
            const float4 sv = *(const float4*)(src + 4 * lane + 256 * ch);
            s += wv.x * sv.x + wv.y * sv.y + wv.z * sv.z + wv.w * sv.w;
        }
#pragma unroll
        for (int off = 1; off < 64; off <<= 1) s += __shfl_xor(s, off);
        if (lane == 0) {
            s = fmaxf(s, 0.f);
            if (u < 64) ha[row] = s; else hm[row] = s;
        }
    }
    __syncthreads();
    {
        const float4* w2 = (const float4*)(caw2 + (size_t)t * 64);
        float s = 0.f;
#pragma unroll
        for (int j = 0; j < 16; ++j) {
            const float4 wv = w2[j];
            s += wv.x * (ha[j * 4 + 0] + hm[j * 4 + 0]);
            s += wv.y * (ha[j * 4 + 1] + hm[j * 4 + 1]);
            s += wv.z * (ha[j * 4 + 2] + hm[j * 4 + 2]);
            s += wv.w * (ha[j * 4 + 3] + hm[j * 4 + 3]);
        }
        s_att[b * C + t] = 1.0f / (1.0f + expf(-s));
    }
}

// ---------------- K9: fused {row avg/max} + {weight folding} — wave-per-row, no barriers
// blocks [0, M/4): 4 waves x 1 row each (lane = 16 channels, uint4 loads, shfl reduce).
// blocks [M/4, M/4+B*D/4): 4 waves x 1 (b,d) fold-row each.
__global__ __launch_bounds__(256) void yqfold_kernel(const u16* __restrict__ t2b,
                                                     const float* __restrict__ scale2,
                                                     const float* __restrict__ shift2,
                                                     const float* __restrict__ s_att,
                                                     const float* __restrict__ pw,
                                                     float* __restrict__ avg_o,
                                                     float* __restrict__ max_o,
                                                     u16* __restrict__ pwb,
                                                     float* __restrict__ bias2) {
    const int bid = blockIdx.x;
    const int t = threadIdx.x;
    const int wave = t >> 6, lane = t & 63;
    const int c0 = lane * 16;            // 16 channels per lane
    const float4* scp = (const float4*)(scale2 + c0);
    const float4* shp = (const float4*)(shift2 + c0);
    if (bid < M / 4) {
        const int row = bid * 4 + wave;
        const int b = row >> 10;
        const u16* tr = t2b + (size_t)row * C + c0;
        const uint4 va = *(const uint4*)tr;
        const uint4 vb = *(const uint4*)(tr + 8);
        const float4* sap = (const float4*)(s_att + (size_t)b * C + c0);
        const u32 words[8] = {va.x, va.y, va.z, va.w, vb.x, vb.y, vb.z, vb.w};
        float s = 0.f, mx = -INFINITY;
#pragma unroll
        for (int q = 0; q < 4; ++q) {
            const float4 sc4 = scp[q], sh4 = shp[q], sa4 = sap[q];
            const u32 lo = words[2 * q], hi = words[2 * q + 1];
            const float y0 = fmaf(bf2f((u16)(lo & 0xffff)), sc4.x, sh4.x) * sa4.x;
            const float y1 = fmaf(bf2f((u16)(lo >> 16)),    sc4.y, sh4.y) * sa4.y;
            const float y2 = fmaf(bf2f((u16)(hi & 0xffff)), sc4.z, sh4.z) * sa4.z;
            const float y3 = fmaf(bf2f((u16)(hi >> 16)),    sc4.w, sh4.w) * sa4.w;
            s += (y0 + y1) + (y2 + y3);
            mx = fmaxf(mx, fmaxf(fmaxf(y0, y1), fmaxf(y2, y3)));
        }
#pragma unroll
        for (int off = 1; off < 64; off <<= 1) {
            s += __shfl_xor(s, off);
            mx = fmaxf(mx, __shfl_xor(mx, off));
        }
        if (lane == 0) {
            avg_o[row] = s * (1.0f / (float)C);
            max_o[row] = mx;
        }
    } else {
        const int bd = (bid - M / 4) * 4 + wave;    // 0..2047
        const int b = bd >> 8;
        const int d = bd & 255;
        const float4* pwp = (const float4*)(pw + (size_t)d * C + c0);
        const float4* sap = (const float4*)(s_att + (size_t)b * C + c0);
        u32 o[8];
        float s = 0.f;
#pragma unroll
        for (int q = 0; q < 4; ++q) {
            const float4 w4 = pwp[q], sc4 = scp[q], sh4 = shp[q], sa4 = sap[q];
            const float f0 = w4.x * sc4.x * sa4.x;
            const float f1 = w4.y * sc4.y * sa4.y;
            const float f2 = w4.z * sc4.z * sa4.z;
            const float f3 = w4.w * sc4.w * sa4.w;
            o[2 * q]     = ((u32)f2bf(f0)) | ((u32)f2bf(f1) << 16);
            o[2 * q + 1] = ((u32)f2bf(f2)) | ((u32)f2bf(f3) << 16);
            s += w4.x * sh4.x * sa4.x + w4.y * sh4.y * sa4.y
               + w4.z * sh4.z * sa4.z + w4.w * sh4.w * sa4.w;
        }
        u16* pwbr = pwb + ((size_t)b * D + d) * C + c0;
        *(uint4*)pwbr = *(uint4*)&o[0];
        *(uint4*)(pwbr + 8) = *(uint4*)&o[4];
#pragma unroll
        for (int off = 1; off < 64; off <<= 1) s += __shfl_xor(s, off);
        if (lane == 0) bias2[bd] = s;
    }
}

// ---------------- K15: final residual add + fused BN3 stats ----------------
__global__ __launch_bounds__(256) void final_kernel(const float* __restrict__ x,
                                                    const float* __restrict__ pre,
                                                    const float* __restrict__ chsum3,
                                                    const float* __restrict__ chsq3,
                                                    const float* __restrict__ g3,
                                                    const float* __restrict__ be3,
                                                    float* __restrict__ out) {
    __shared__ float lsc[256], lsh[256];
    const int t = threadIdx.x;
    {
        const float m = chsum3[t] * (1.0f / (float)M);
        const float var = chsq3[t] * (1.0f / (float)M) - m * m;
        const float rstd = rsqrtf(var + EPS);
        const float sc = rstd * g3[t];
        lsc[t] = sc;
        lsh[t] = be3[t] - m * sc;
    }
    __syncthreads();
    const int i = blockIdx.x * 256 + t;   // float4 index
    const int e = i * 4;
    const int d = e & 255;
    const float4 xv = *(const float4*)(x + e);
    const float4 pv = *(const float4*)(pre + e);
    const float4 sc = *(const float4*)(lsc + d);
    const float4 sh = *(const float4*)(lsh + d);
    float4 o;
    o.x = xv.x + fmaf(pv.x, sc.x, sh.x);
    o.y = xv.y + fmaf(pv.y, sc.y, sh.y);
    o.z = xv.z + fmaf(pv.z, sc.z, sh.z);
    o.w = xv.w + fmaf(pv.w, sc.w, sh.w);
    *(float4*)(out + e) = o;
}

extern "C" void kernel_launch(void* const* d_in, const int* in_sizes, int n_in,
                              void* d_out, int out_size, void* d_ws, size_t ws_size,
                              hipStream_t stream) {
    const float* x    = (const float*)d_in[0];
    const float* w1   = (const float*)d_in[1];
    const float* b1   = (const float*)d_in[2];
    const float* g1   = (const float*)d_in[3];
    const float* be1  = (const float*)d_in[4];
    const float* aw1  = (const float*)d_in[5];
    const float* ab1  = (const float*)d_in[6];
    const float* aw2  = (const float*)d_in[7];
    const float* ab2  = (const float*)d_in[8];
    const float* g2   = (const float*)d_in[9];
    const float* be2  = (const float*)d_in[10];
    const float* caw1 = (const float*)d_in[11];
    const float* caw2 = (const float*)d_in[12];
    const float* pw   = (const float*)d_in[13];
    const float* pb   = (const float*)d_in[14];
    const float* g3   = (const float*)d_in[15];
    const float* be3  = (const float*)d_in[16];
    const float* sw   = (const float*)d_in[17];
    const float* sb   = (const float*)d_in[18];
    float* out = (float*)d_out;
    float* ws = (float*)d_ws;

    float* chsum1  = ws + WS_CHSUM1;
    float* chsq1   = ws + WS_CHSQ1;
    float* gapsum  = ws + WS_GAPSUM;
    float* chsum3  = ws + WS_CHSUM3;
    float* chsq3   = ws + WS_CHSQ3;
    float* chsum2  = ws + WS_CHSUM2;
    float* chsq2   = ws + WS_CHSQ2;
    float* bsum2   = ws + WS_BSUM2;
    u32*   umax2   = (u32*)(ws + WS_UMAX2);
    u32*   umaxn2  = (u32*)(ws + WS_UMAXN2);
    float* scale1  = ws + WS_SCALE1;
    float* shift1  = ws + WS_SHIFT1;
    float* kw      = ws + WS_KW;
    float* scale2  = ws + WS_SCALE2;
    float* shift2  = ws + WS_SHIFT2;
    float* s_att   = ws + WS_SATT;
    float* avg_o   = ws + WS_AVGO;
    float* max_o   = ws + WS_MAXO;
    float* pre     = ws + WS_PRE;
    float* bias2   = ws + WS_BIAS2;
    u16* t1b  = (u16*)(ws + WS_T1B);
    u16* t2b  = (u16*)(ws + WS_T2B);
    u16* xb   = (u16*)(ws + WS_XB);
    u16* w1b  = (u16*)(ws + WS_W1B);
    u16* pwbf = (u16*)(ws + WS_PWBF);

    // K0: zero accumulators + casts (x, w1)
    cvt_all_kernel<<<dim3(2304), 256, 0, stream>>>(x, w1, xb, w1b, ws);
    // K1: expand GEMM (128x64 tile, BK=32 3-buffer 2-deep pipeline + setprio).
    //     1024 blocks, dyn LDS = 36864 B -> 4 blocks/CU, 16 waves/CU
    mfma_gemm_kernel<256, 0, C, 128, 64, 1><<<dim3(C / 64, M / 128), 256, 36864, stream>>>(
        xb, w1b, b1, nullptr, nullptr, nullptr, nullptr, nullptr,
        t1b, chsum1, chsq1, gapsum);
    // K4: BN1 stats + gap + dynamic kernel weights (fused)
    dynmlp_kernel<<<dim3(B), 1024, 0, stream>>>(chsum1, chsq1, gapsum, g1, be1,
                                                aw1, ab1, aw2, ab2, scale1, shift1, kw);
    // K5: depthwise conv (sliding-window regs, h-band XCD swizzle) -> bf16 t2, BN2 atomics
    dwconv_kernel<<<dim3(4, B * H), 256, 0, stream>>>(t1b, scale1, shift1, kw, t2b,
                                                      chsum2, chsq2, bsum2, umax2, umaxn2);
    // K8: BN2 finalize + channel attention (s_att only)
    chatt_kernel<<<dim3(B), 1024, 0, stream>>>(chsum2, chsq2, bsum2, umax2, umaxn2,
                                               g2, be2, caw1, caw2, scale2, shift2, s_att);
    // K9: fused yq + fold, wave-per-row (no barriers). 2048 + 512 blocks.
    yqfold_kernel<<<dim3(M / 4 + (B * D) / 4), 256, 0, stream>>>(
        t2b, scale2, shift2, s_att, pw, avg_o, max_o, pwbf, bias2);
    // K12: project GEMM, 512-thread blocks, intra-block K-split (2 groups x 16 chunks)
    //      + setprio. 256 blocks -> 2 blocks/CU, 16 waves/CU. Dyn LDS = 77312 B
    mfma_gemm_kernel<1024, 1, D, 128, 64, 2><<<dim3(D / 64, M / 128), 512, 77312, stream>>>(
        t2b, pwbf, bias2, pb, avg_o, max_o, sw, sb,
        pre, chsum3, chsq3, nullptr);
    // K15: BN3 stats + final residual add (fused)
    final_kernel<<<dim3((M * D / 4) / 256), 256, 0, stream>>>(x, pre, chsum3, chsq3, g3, be3, out);
}